// Round 8
// baseline (329.692 us; speedup 1.0000x reference)
//
#include <hip/hip_runtime.h>
#include <hip/hip_bf16.h>
#include <hip/hip_cooperative_groups.h>
#include <math.h>

namespace cg = cooperative_groups;

#define BB 128
#define TT 64
#define DD 64
#define HH 128
#define NHH 4
#define K3H 384        // 3*H

typedef __attribute__((ext_vector_type(8))) short short8_t;   // 8 bf16
typedef __attribute__((ext_vector_type(4))) float float4_t;

#define LOG2E 1.4426950408889634f

__device__ __forceinline__ unsigned short f2bf(float f) {
    unsigned int u = __float_as_uint(f);
    u += 0x7fffu + ((u >> 16) & 1u);      // RNE
    return (unsigned short)(u >> 16);
}

// hardware packed convert: v_cvt_pk_bf16_f32 (RNE, bit-identical to f2bf)
__device__ __forceinline__ unsigned pack_bf2_hw(float lo, float hi) {
    __hip_bfloat162 p = __float22bfloat162_rn(make_float2(lo, hi));
    unsigned u;
    __builtin_memcpy(&u, &p, 4);
    return u;
}

// single-value hw convert: 1 VALU op (vs 4 for software f2bf)
__device__ __forceinline__ unsigned short f2bf_hw(float f) {
    return (unsigned short)(pack_bf2_hw(f, f) & 0xffffu);
}

__device__ __forceinline__ float bf2f(unsigned short s) {
    return __uint_as_float((unsigned)s << 16);
}

// packed-pair fp32 helpers (SLP -> v_pk_fma_f32 / v_pk_add_f32)
__device__ __forceinline__ float2 pk_fma(float2 a, float2 b, float2 c) {
    return make_float2(fmaf(a.x, b.x, c.x), fmaf(a.y, b.y, c.y));
}
__device__ __forceinline__ float2 pk_sub(float2 a, float2 b) {
    return make_float2(a.x - b.x, a.y - b.y);
}

// Shared-reciprocal z/tanh epilogue (verified R4, absmax unchanged).
__device__ __forceinline__ void gru_epilogue(
    const float4_t& ar, const float4_t& az, const float4_t& an, float xv,
    const float wrs[4], const float wzs[4], const float wns[4],
    const float bnis[4], float hprev[4], float hn4[4])
{
    float2 xv2 = make_float2(xv, xv);
#pragma unroll
    for (int pp = 0; pp < 2; ++pp) {
        const int r0 = 2 * pp, r1 = r0 + 1;
        float2 grs = pk_fma(xv2, make_float2(wrs[r0], wrs[r1]),
                            make_float2(ar[r0], ar[r1]));
        float2 gzs = pk_fma(xv2, make_float2(wzs[r0], wzs[r1]),
                            make_float2(az[r0], az[r1]));
        float2 rg = make_float2(
            __builtin_amdgcn_rcpf(1.f + __builtin_amdgcn_exp2f(grs.x)),
            __builtin_amdgcn_rcpf(1.f + __builtin_amdgcn_exp2f(grs.y)));
        float2 gns = pk_fma(rg, make_float2(an[r0], an[r1]),
                            pk_fma(xv2, make_float2(wns[r0], wns[r1]),
                                   make_float2(bnis[r0], bnis[r1])));
        float2 t1 = make_float2(1.f + __builtin_amdgcn_exp2f(gns.x),
                                1.f + __builtin_amdgcn_exp2f(gns.y));
        float2 t2 = make_float2(1.f + __builtin_amdgcn_exp2f(gzs.x),
                                1.f + __builtin_amdgcn_exp2f(gzs.y));
        float2 iD = make_float2(__builtin_amdgcn_rcpf(t1.x * t2.x),
                                __builtin_amdgcn_rcpf(t1.y * t2.y));
        float2 tn = make_float2(fmaf(-2.f, t2.x * iD.x, 1.f),
                                fmaf(-2.f, t2.y * iD.y, 1.f));
        float2 zg = make_float2(t1.x * iD.x, t1.y * iD.y);
        float2 hp = make_float2(hprev[r0], hprev[r1]);
        float2 hn = pk_fma(zg, pk_sub(hp, tn), tn);
        hprev[r0] = hn.x; hprev[r1] = hn.y;
        hn4[r0] = hn.x; hn4[r1] = hn.y;
    }
}

// ---- tail helpers (R7, hw converts) --------------------------------------
__device__ __forceinline__ void load_wfrag(const float* __restrict__ Wp, int N,
                                           int col, float scale, int q,
                                           short8_t fr[4])
{
#pragma unroll
    for (int kc = 0; kc < 4; ++kc) {
        const float* p = Wp + (size_t)(kc * 32 + q * 8) * N + col;
        unsigned u[4];
#pragma unroll
        for (int j = 0; j < 4; ++j)
            u[j] = pack_bf2_hw(p[(size_t)(2 * j) * N] * scale,
                               p[(size_t)(2 * j + 1) * N] * scale);
        short8_t f;
        __builtin_memcpy(&f, u, 16);
        fr[kc] = f;
    }
}

__device__ __forceinline__ void load_afrag(const unsigned short (*S)[136],
                                           short8_t Af[4][4], int m16, int q)
{
#pragma unroll
    for (int mt = 0; mt < 4; ++mt)
#pragma unroll
        for (int kc = 0; kc < 4; ++kc)
            Af[mt][kc] = *(const short8_t*)&S[mt * 16 + m16][kc * 32 + q * 8];
}

__device__ __forceinline__ void mm_regw(short8_t Af[4][4], short8_t Bf[4],
                                        float4_t acc[4])
{
#pragma unroll
    for (int mt = 0; mt < 4; ++mt) {
        float4_t a = acc[mt];
#pragma unroll
        for (int kc = 0; kc < 4; ++kc)
            a = __builtin_amdgcn_mfma_f32_16x16x32_bf16(Af[mt][kc], Bf[kc], a, 0, 0, 0);
        acc[mt] = a;
    }
}

__device__ __forceinline__ void zero4(float4_t acc[4]) {
#pragma unroll
    for (int mt = 0; mt < 4; ++mt) acc[mt] = (float4_t){0.f, 0.f, 0.f, 0.f};
}

__device__ __forceinline__ void store_rows(unsigned short (*Dst)[136], float4_t acc[4],
                                           float bv, int relu, int col, int q)
{
#pragma unroll
    for (int mt = 0; mt < 4; ++mt)
#pragma unroll
        for (int reg = 0; reg < 4; ++reg) {
            float v = acc[mt][reg] + bv;
            if (relu) v = fmaxf(v, 0.f);
            Dst[mt * 16 + q * 4 + reg][col] = f2bf_hw(v);
        }
}

// ---- fused LDS: gru phase and tail phase overlay -------------------------
union SharedU {
    struct {
        unsigned short hbuf[2][2][16][144];   // [grp][parity]
        float xs_t[TT][32];
        int tstar[32];
    } g;                                      // 26.8 KB
    struct {
        unsigned short E[64][136];
        unsigned short Qs[64][136];
        unsigned short Ks[64][136];
        unsigned short Vt[128][72];
        float sc4[4][64][66];
        float lnp[64][8], lnp2[64][8];
        float mean_s[64], rs_s[64];
        float fq_s[128], fo_s[128], e_s[64], red_s[256];
    } t;                                      // 145.2 KB
};

// ===========================================================================
// Fused cooperative kernel: R6 gru (88us, frozen) -> grid sync -> R7 tail.
// Both phases already ran at 1 block/CU; union LDS (145KB) preserves that,
// so the 256-block cooperative grid is exactly co-resident.  This removes
// the kernel boundary (probing the ~50us/iter that is neither kernel) and
// surfaces the tail phase in the profiled dispatch for the first time.
// ===========================================================================
__global__ __launch_bounds__(512, 1) void fused_kernel(
    const float* __restrict__ x, const int* __restrict__ mask,
    const float* __restrict__ Wih, const float* __restrict__ Whh,
    const float* __restrict__ bih, const float* __restrict__ bhh,
    const float* __restrict__ Wq, const float* __restrict__ bq,
    const float* __restrict__ Wk, const float* __restrict__ bk,
    const float* __restrict__ Wv, const float* __restrict__ bv,
    const float* __restrict__ Wo, const float* __restrict__ bo,
    const float* __restrict__ W1, const float* __restrict__ b1,
    const float* __restrict__ W2, const float* __restrict__ b2,
    const float* __restrict__ g1, const float* __restrict__ be1,
    const float* __restrict__ g2, const float* __restrict__ be2,
    const float* __restrict__ Fq, const float* __restrict__ fbq,
    const float* __restrict__ Fk, const float* __restrict__ fbk,
    const float* __restrict__ Fv, const float* __restrict__ fbv,
    const float* __restrict__ Fout, const float* __restrict__ fbout,
    float* __restrict__ emb, float* __restrict__ out)
{
    __shared__ __align__(16) SharedU smem;
    const int bid = blockIdx.x;
    const int tid = threadIdx.x;

    // ===================== PHASE 1: GRU (all 256 blocks) ==================
    {
        const int d  = bid & 63;
        const int b0 = (bid >> 6) * 32;
        const int w = tid >> 6;
        const int l = tid & 63;
        const int m = l & 15;
        const int q = l >> 4;

        unsigned short (&hbuf)[2][2][16][144] = smem.g.hbuf;
        float (&xs_t)[TT][32] = smem.g.xs_t;
        int (&tstar_s)[32] = smem.g.tstar;

        for (int idx = tid; idx < 32 * TT; idx += 512) {
            int t = idx >> 5, row = idx & 31;
            xs_t[t][row] = x[((size_t)(b0 + row) * TT + t) * DD + d];
        }
        if (tid < 32) {
            int b = b0 + tid, len = 0;
            for (int t = 0; t < TT; ++t) len += mask[b * TT + t];
            int ts = len - 1;
            if (ts < 0) ts = 0;
            if (ts > TT - 1) ts = TT - 1;
            tstar_s[tid] = ts;
        }
        for (int idx = tid; idx < 2 * 2 * 16 * 144; idx += 512)
            ((unsigned short*)hbuf)[idx] = 0;

        short8_t Wf[3][4];
#pragma unroll
        for (int g = 0; g < 3; ++g) {
            float sc = (g == 2) ? (2.f * LOG2E) : (-LOG2E);
            int kcol = g * HH + 16 * w + m;
            const float* wrow = Whh + ((size_t)d * K3H + kcol) * HH;
#pragma unroll
            for (int kc = 0; kc < 4; ++kc) {
                int j0 = kc * 32 + q * 8;
                float4 w0 = *(const float4*)(wrow + j0);
                float4 w1 = *(const float4*)(wrow + j0 + 4);
                short8_t f;
                f[0] = (short)f2bf(w0.x * sc); f[1] = (short)f2bf(w0.y * sc);
                f[2] = (short)f2bf(w0.z * sc); f[3] = (short)f2bf(w0.w * sc);
                f[4] = (short)f2bf(w1.x * sc); f[5] = (short)f2bf(w1.y * sc);
                f[6] = (short)f2bf(w1.z * sc); f[7] = (short)f2bf(w1.w * sc);
                Wf[g][kc] = f;
            }
        }

        const int hcol0 = 16 * w + q * 4;
        float4 wr4 = *(const float4*)&Wih[d * K3H + hcol0];
        float4 wz4 = *(const float4*)&Wih[d * K3H + HH + hcol0];
        float4 wn4 = *(const float4*)&Wih[d * K3H + 2 * HH + hcol0];
        float4 br4 = *(const float4*)&bih[d * K3H + hcol0];
        float4 bz4 = *(const float4*)&bih[d * K3H + HH + hcol0];
        float4 bni4 = *(const float4*)&bih[d * K3H + 2 * HH + hcol0];
        float4 bhr4 = *(const float4*)&bhh[d * K3H + hcol0];
        float4 bhz4 = *(const float4*)&bhh[d * K3H + HH + hcol0];
        float4 bnh4 = *(const float4*)&bhh[d * K3H + 2 * HH + hcol0];
        float brs[4], bzs[4], bnis[4], bnhs[4], wrs[4], wzs[4], wns[4];
#pragma unroll
        for (int r = 0; r < 4; ++r) {
            wrs[r] = -LOG2E * ((const float*)&wr4)[r];
            wzs[r] = -LOG2E * ((const float*)&wz4)[r];
            wns[r] = 2.f * LOG2E * ((const float*)&wn4)[r];
            brs[r] = -LOG2E * (((const float*)&br4)[r] + ((const float*)&bhr4)[r]);
            bzs[r] = -LOG2E * (((const float*)&bz4)[r] + ((const float*)&bhz4)[r]);
            bnis[r] = 2.f * LOG2E * ((const float*)&bni4)[r];
            bnhs[r] = 2.f * LOG2E * ((const float*)&bnh4)[r];
        }

        float hprevA[4], hprevB[4];
#pragma unroll
        for (int i = 0; i < 4; ++i) { hprevA[i] = 0.f; hprevB[i] = 0.f; }

        __syncthreads();                       // hbuf zero-init visible
        const int tstarA = tstar_s[m];
        const int tstarB = tstar_s[16 + m];
        float* embpA = emb + (((size_t)(b0 + m)) * DD + d) * HH + hcol0;
        float* embpB = emb + (((size_t)(b0 + 16 + m)) * DD + d) * HH + hcol0;

        short8_t hfA[4];
#pragma unroll
        for (int kc = 0; kc < 4; ++kc)
            hfA[kc] = *(const short8_t*)&hbuf[0][0][m][kc * 32 + q * 8];
        float4_t arA = {brs[0], brs[1], brs[2], brs[3]};
        float4_t azA = {bzs[0], bzs[1], bzs[2], bzs[3]};
        float4_t anA = {bnhs[0], bnhs[1], bnhs[2], bnhs[3]};
#pragma unroll
        for (int kc = 0; kc < 4; ++kc) {
            arA = __builtin_amdgcn_mfma_f32_16x16x32_bf16(Wf[0][kc], hfA[kc], arA, 0, 0, 0);
            azA = __builtin_amdgcn_mfma_f32_16x16x32_bf16(Wf[1][kc], hfA[kc], azA, 0, 0, 0);
            anA = __builtin_amdgcn_mfma_f32_16x16x32_bf16(Wf[2][kc], hfA[kc], anA, 0, 0, 0);
        }

        for (int t = 0; t < TT; ++t) {
            const int par = t & 1;
            float hn4[4];
            uint2 uu;

            short8_t hfB[4];
#pragma unroll
            for (int kc = 0; kc < 4; ++kc)
                hfB[kc] = *(const short8_t*)&hbuf[1][par][m][kc * 32 + q * 8];

            gru_epilogue(arA, azA, anA, xs_t[t][m], wrs, wzs, wns, bnis, hprevA, hn4);
            uu.x = pack_bf2_hw(hn4[0], hn4[1]);
            uu.y = pack_bf2_hw(hn4[2], hn4[3]);
            *(uint2*)&hbuf[0][par ^ 1][m][hcol0] = uu;
            if (t == tstarA) {
                float4 hv; hv.x = hn4[0]; hv.y = hn4[1]; hv.z = hn4[2]; hv.w = hn4[3];
                *(float4*)embpA = hv;
            }

            float4_t arB = {brs[0], brs[1], brs[2], brs[3]};
            float4_t azB = {bzs[0], bzs[1], bzs[2], bzs[3]};
            float4_t anB = {bnhs[0], bnhs[1], bnhs[2], bnhs[3]};
#pragma unroll
            for (int kc = 0; kc < 4; ++kc) {
                arB = __builtin_amdgcn_mfma_f32_16x16x32_bf16(Wf[0][kc], hfB[kc], arB, 0, 0, 0);
                azB = __builtin_amdgcn_mfma_f32_16x16x32_bf16(Wf[1][kc], hfB[kc], azB, 0, 0, 0);
                anB = __builtin_amdgcn_mfma_f32_16x16x32_bf16(Wf[2][kc], hfB[kc], anB, 0, 0, 0);
            }

            gru_epilogue(arB, azB, anB, xs_t[t][16 + m], wrs, wzs, wns, bnis, hprevB, hn4);
            uu.x = pack_bf2_hw(hn4[0], hn4[1]);
            uu.y = pack_bf2_hw(hn4[2], hn4[3]);
            *(uint2*)&hbuf[1][par ^ 1][m][hcol0] = uu;
            if (t == tstarB) {
                float4 hv; hv.x = hn4[0]; hv.y = hn4[1]; hv.z = hn4[2]; hv.w = hn4[3];
                *(float4*)embpB = hv;
            }

            __syncthreads();

            if (t < TT - 1) {
#pragma unroll
                for (int kc = 0; kc < 4; ++kc)
                    hfA[kc] = *(const short8_t*)&hbuf[0][par ^ 1][m][kc * 32 + q * 8];
                arA = (float4_t){brs[0], brs[1], brs[2], brs[3]};
                azA = (float4_t){bzs[0], bzs[1], bzs[2], bzs[3]};
                anA = (float4_t){bnhs[0], bnhs[1], bnhs[2], bnhs[3]};
#pragma unroll
                for (int kc = 0; kc < 4; ++kc) {
                    arA = __builtin_amdgcn_mfma_f32_16x16x32_bf16(Wf[0][kc], hfA[kc], arA, 0, 0, 0);
                    azA = __builtin_amdgcn_mfma_f32_16x16x32_bf16(Wf[1][kc], hfA[kc], azA, 0, 0, 0);
                    anA = __builtin_amdgcn_mfma_f32_16x16x32_bf16(Wf[2][kc], hfA[kc], anA, 0, 0, 0);
                }
            }
        }
    }

    // ================ grid-wide handoff: emb visible everywhere ===========
    __threadfence();
    cg::this_grid().sync();

    // ===================== PHASE 2: tail (blocks 0..127) ==================
    if (bid >= BB) return;
    {
        const int b = bid;
        const int w = tid >> 6, l = tid & 63, m16 = l & 15, q = l >> 4;
        const int col = w * 16 + m16;

        unsigned short (&E)[64][136]  = smem.t.E;
        unsigned short (&Qs)[64][136] = smem.t.Qs;
        unsigned short (&Ks)[64][136] = smem.t.Ks;
        unsigned short (&Vt)[128][72] = smem.t.Vt;
        float (&sc4)[4][64][66] = smem.t.sc4;
        float (&lnp)[64][8] = smem.t.lnp;
        float (&lnp2)[64][8] = smem.t.lnp2;
        float (&mean_s)[64] = smem.t.mean_s;
        float (&rs_s)[64] = smem.t.rs_s;
        float (&fq_s)[128] = smem.t.fq_s;
        float (&fo_s)[128] = smem.t.fo_s;
        float (&e_s)[64] = smem.t.e_s;
        float (&red_s)[256] = smem.t.red_s;

        const float* embB = emb + (size_t)b * 64 * 128;
        const float SS = 0.17677669529663687f;   // 1/sqrt(32)

        short8_t WqF[4], WkF[4], WvF[4];
        load_wfrag(Wq, 128, col, SS, q, WqF);
        load_wfrag(Wk, 128, col, 1.f, q, WkF);
        load_wfrag(Wv, 128, col, 1.f, q, WvF);
        float bqv = bq[col] * SS, bkv = bk[col], bvv = bv[col];

        for (int it = tid; it < 2048; it += 512) {
            int r = it >> 5, c4 = (it & 31) << 2;
            float4 a = *(const float4*)&embB[r * 128 + c4];
            uint2 p; p.x = pack_bf2_hw(a.x, a.y); p.y = pack_bf2_hw(a.z, a.w);
            *(uint2*)&E[r][c4] = p;
        }
        __syncthreads();                                   // B0

        short8_t Af[4][4];
        float4_t acc[4];
        load_afrag(E, Af, m16, q);

        zero4(acc); mm_regw(Af, WqF, acc); store_rows(Qs, acc, bqv, 0, col, q);
        zero4(acc); mm_regw(Af, WkF, acc); store_rows(Ks, acc, bkv, 0, col, q);
        zero4(acc); mm_regw(Af, WvF, acc);
#pragma unroll
        for (int mt = 0; mt < 4; ++mt) {
            uint2 pk;
            pk.x = pack_bf2_hw(acc[mt][0] + bvv, acc[mt][1] + bvv);
            pk.y = pack_bf2_hw(acc[mt][2] + bvv, acc[mt][3] + bvv);
            *(uint2*)&Vt[col][mt * 16 + q * 4] = pk;
        }
        __syncthreads();                                   // B1

        short8_t WoF[4], W1aF[4], W1bF[4];
        load_wfrag(Wo, 128, col, 1.f, q, WoF);
        load_wfrag(W1, 256, col, 1.f, q, W1aF);
        load_wfrag(W1, 256, 128 + col, 1.f, q, W1bF);
        float bov = bo[col], b1a = b1[col], b1b = b1[128 + col];
        float g1v = g1[col], be1v = be1[col];

        {
            int hd = w >> 1, ntb = (w & 1) * 2;
#pragma unroll
            for (int mt = 0; mt < 4; ++mt) {
                short8_t Aq = *(const short8_t*)&Qs[mt * 16 + m16][hd * 32 + q * 8];
#pragma unroll
                for (int nn = 0; nn < 2; ++nn) {
                    int nt = ntb + nn;
                    short8_t Bk = *(const short8_t*)&Ks[nt * 16 + m16][hd * 32 + q * 8];
                    float4_t a = {0.f, 0.f, 0.f, 0.f};
                    a = __builtin_amdgcn_mfma_f32_16x16x32_bf16(Aq, Bk, a, 0, 0, 0);
#pragma unroll
                    for (int reg = 0; reg < 4; ++reg)
                        sc4[hd][mt * 16 + q * 4 + reg][nt * 16 + m16] = a[reg];
                }
            }
        }
        __syncthreads();                                   // B2

        {
            int pr = tid >> 1, hd2 = pr >> 6, row = pr & 63, half = (tid & 1) * 32;
            float v[32]; float mx = -1e30f;
#pragma unroll
            for (int c = 0; c < 32; ++c) { v[c] = sc4[hd2][row][half + c]; mx = fmaxf(mx, v[c]); }
            mx = fmaxf(mx, __shfl_xor(mx, 1));
            float sum = 0.f;
#pragma unroll
            for (int c = 0; c < 32; ++c) { v[c] = __expf(v[c] - mx); sum += v[c]; }
            sum += __shfl_xor(sum, 1);
            float inv = __builtin_amdgcn_rcpf(sum);
            unsigned short (*Pd)[136] = (hd2 < 2) ? Qs : Ks;
            int cb = (hd2 & 1) * 64 + half;
#pragma unroll
            for (int c = 0; c < 16; ++c)
                *(unsigned*)&Pd[row][cb + 2 * c] = pack_bf2_hw(v[2 * c] * inv, v[2 * c + 1] * inv);
        }
        __syncthreads();                                   // B3

        {
            int hd = w >> 1, nt = w & 1;
            const unsigned short (*P)[136] = (hd < 2) ? (const unsigned short (*)[136])Qs
                                                      : (const unsigned short (*)[136])Ks;
            int pb = (hd & 1) * 64;
            int vrow = hd * 32 + nt * 16 + m16;
            short8_t B0f = *(const short8_t*)&Vt[vrow][q * 8];
            short8_t B1f = *(const short8_t*)&Vt[vrow][32 + q * 8];
#pragma unroll
            for (int mt = 0; mt < 4; ++mt) {
                short8_t A0 = *(const short8_t*)&P[mt * 16 + m16][pb + q * 8];
                short8_t A1 = *(const short8_t*)&P[mt * 16 + m16][pb + 32 + q * 8];
                float4_t a = {0.f, 0.f, 0.f, 0.f};
                a = __builtin_amdgcn_mfma_f32_16x16x32_bf16(A0, B0f, a, 0, 0, 0);
                a = __builtin_amdgcn_mfma_f32_16x16x32_bf16(A1, B1f, a, 0, 0, 0);
#pragma unroll
                for (int reg = 0; reg < 4; ++reg)
                    E[mt * 16 + q * 4 + reg][vrow] = f2bf_hw(a[reg]);
            }
        }
        __syncthreads();                                   // B4

        short8_t W2aF[4], W2bF[4], FkF[4], FvF[4];
        load_wfrag(W2, 128, col, 1.f, q, W2aF);
        load_wfrag(W2 + (size_t)128 * 128, 128, col, 1.f, q, W2bF);
        load_wfrag(Fk, 128, col, 1.f, q, FkF);
        load_wfrag(Fv, 128, col, 1.f, q, FvF);
        float b2v = b2[col], fbkv = fbk[col], fbvv = fbv[col];
        float g2v = g2[col], be2v = be2[col];

        load_afrag(E, Af, m16, q);
        zero4(acc); mm_regw(Af, WoF, acc);
        float h1v[4][4];
#pragma unroll
        for (int mt = 0; mt < 4; ++mt)
#pragma unroll
            for (int reg = 0; reg < 4; ++reg) {
                int row = mt * 16 + q * 4 + reg;
                h1v[mt][reg] = acc[mt][reg] + bov + embB[(size_t)row * 128 + col];
            }
#pragma unroll
        for (int mt = 0; mt < 4; ++mt)
#pragma unroll
            for (int reg = 0; reg < 4; ++reg) {
                float s = h1v[mt][reg], s2 = s * s;
                s += __shfl_xor(s, 1); s += __shfl_xor(s, 2); s += __shfl_xor(s, 4); s += __shfl_xor(s, 8);
                s2 += __shfl_xor(s2, 1); s2 += __shfl_xor(s2, 2); s2 += __shfl_xor(s2, 4); s2 += __shfl_xor(s2, 8);
                if (m16 == 0) { int row = mt * 16 + q * 4 + reg; lnp[row][w] = s; lnp2[row][w] = s2; }
            }
        __syncthreads();                                   // B5
        if (tid < 64) {
            float s = 0.f, s2 = 0.f;
#pragma unroll
            for (int k = 0; k < 8; ++k) { s += lnp[tid][k]; s2 += lnp2[tid][k]; }
            float mn = s * (1.f / 128.f);
            mean_s[tid] = mn;
            rs_s[tid] = rsqrtf(s2 * (1.f / 128.f) - mn * mn + 1e-5f);
        }
        __syncthreads();                                   // B6
#pragma unroll
        for (int mt = 0; mt < 4; ++mt)
#pragma unroll
            for (int reg = 0; reg < 4; ++reg) {
                int row = mt * 16 + q * 4 + reg;
                float hv = (h1v[mt][reg] - mean_s[row]) * rs_s[row] * g1v + be1v;
                h1v[mt][reg] = hv;
                E[row][col] = f2bf_hw(hv);
            }
        __syncthreads();                                   // B7

        load_afrag(E, Af, m16, q);
        zero4(acc); mm_regw(Af, W1aF, acc); store_rows(Qs, acc, b1a, 1, col, q);
        zero4(acc); mm_regw(Af, W1bF, acc); store_rows(Ks, acc, b1b, 1, col, q);
        __syncthreads();                                   // B8

        {
            short8_t AfQ[4][4], AfK[4][4];
            load_afrag(Qs, AfQ, m16, q);
            load_afrag(Ks, AfK, m16, q);
            zero4(acc); mm_regw(AfQ, W2aF, acc); mm_regw(AfK, W2bF, acc);
        }
#pragma unroll
        for (int mt = 0; mt < 4; ++mt)
#pragma unroll
            for (int reg = 0; reg < 4; ++reg)
                h1v[mt][reg] = acc[mt][reg] + b2v + h1v[mt][reg];
#pragma unroll
        for (int mt = 0; mt < 4; ++mt)
#pragma unroll
            for (int reg = 0; reg < 4; ++reg) {
                float s = h1v[mt][reg], s2 = s * s;
                s += __shfl_xor(s, 1); s += __shfl_xor(s, 2); s += __shfl_xor(s, 4); s += __shfl_xor(s, 8);
                s2 += __shfl_xor(s2, 1); s2 += __shfl_xor(s2, 2); s2 += __shfl_xor(s2, 4); s2 += __shfl_xor(s2, 8);
                if (m16 == 0) { int row = mt * 16 + q * 4 + reg; lnp[row][w] = s; lnp2[row][w] = s2; }
            }
        __syncthreads();                                   // B9
        if (tid < 64) {
            float s = 0.f, s2 = 0.f;
#pragma unroll
            for (int k = 0; k < 8; ++k) { s += lnp[tid][k]; s2 += lnp2[tid][k]; }
            float mn = s * (1.f / 128.f);
            mean_s[tid] = mn;
            rs_s[tid] = rsqrtf(s2 * (1.f / 128.f) - mn * mn + 1e-5f);
        }
        __syncthreads();                                   // B10
#pragma unroll
        for (int mt = 0; mt < 4; ++mt)
#pragma unroll
            for (int reg = 0; reg < 4; ++reg) {
                int row = mt * 16 + q * 4 + reg;
                float hv = (h1v[mt][reg] - mean_s[row]) * rs_s[row] * g2v + be2v;
                E[row][col] = f2bf_hw(hv);   // h2
            }
        __syncthreads();                                   // B11

        load_afrag(E, Af, m16, q);
        zero4(acc); mm_regw(Af, FkF, acc); store_rows(Qs, acc, fbkv, 0, col, q);
        zero4(acc); mm_regw(Af, FvF, acc); store_rows(Ks, acc, fbvv, 0, col, q);
        {
            int co = tid >> 2, sub = tid & 3;
            float a2 = 0.f;
#pragma unroll 8
            for (int mm2 = sub * 32; mm2 < sub * 32 + 32; ++mm2)
                a2 = fmaf(bf2f(E[63][mm2]), Fq[(size_t)mm2 * 128 + co], a2);
            a2 += __shfl_xor(a2, 1);
            a2 += __shfl_xor(a2, 2);
            if (sub == 0) fq_s[co] = a2 + fbq[co];
        }
        if (tid < 128) fo_s[tid] = Fout[tid];
        __syncthreads();                                   // B12

        {
            int dd = tid >> 3, c8 = tid & 7;
            float p = 0.f;
#pragma unroll
            for (int c = 0; c < 16; ++c) {
                int cc = c8 * 16 + c;
                float t = fq_s[cc] + bf2f(Qs[dd][cc]);
                float tn = 1.f - 2.f * __builtin_amdgcn_rcpf(
                    __builtin_amdgcn_exp2f(2.f * LOG2E * t) + 1.f);
                p = fmaf(tn, fo_s[cc], p);
            }
            p += __shfl_xor(p, 1); p += __shfl_xor(p, 2); p += __shfl_xor(p, 4);
            if (c8 == 0) e_s[dd] = p + fbout[0];
        }
        __syncthreads();                                   // B13
        if (tid < 64) {
            float e = e_s[tid], mx = e;
            for (int o = 32; o; o >>= 1) mx = fmaxf(mx, __shfl_xor(mx, o));
            float pe = __expf(e - mx);
            float s = pe;
            for (int o = 32; o; o >>= 1) s += __shfl_xor(s, o);
            e_s[tid] = pe / s;
        }
        __syncthreads();                                   // B14
        if (tid < 256) {
            int c2 = tid & 127, rg2 = tid >> 7;
            float a = 0.f;
            for (int d2 = rg2 * 32; d2 < rg2 * 32 + 32; ++d2)
                a = fmaf(e_s[d2], bf2f(Ks[d2][c2]), a);
            red_s[tid] = a;
        }
        __syncthreads();                                   // B15
        if (tid < 128)
            out[(size_t)b * 128 + tid] = red_s[tid] + red_s[tid + 128];
    }
}

// ---------------- launch ---------------------------------------------------
extern "C" void kernel_launch(void* const* d_in, const int* in_sizes, int n_in,
                              void* d_out, int out_size, void* d_ws, size_t ws_size,
                              hipStream_t stream)
{
    const float* x    = (const float*)d_in[0];
    const int*   mask = (const int*)d_in[1];
    const float* Wih  = (const float*)d_in[2];
    const float* Whh  = (const float*)d_in[3];
    const float* bih  = (const float*)d_in[4];
    const float* bhh  = (const float*)d_in[5];
    const float* Wq = (const float*)d_in[6];   const float* bq = (const float*)d_in[7];
    const float* Wk = (const float*)d_in[8];   const float* bk = (const float*)d_in[9];
    const float* Wv = (const float*)d_in[10];  const float* bv = (const float*)d_in[11];
    const float* Wo = (const float*)d_in[12];  const float* bo = (const float*)d_in[13];
    const float* W1 = (const float*)d_in[14];  const float* b1 = (const float*)d_in[15];
    const float* W2 = (const float*)d_in[16];  const float* b2 = (const float*)d_in[17];
    const float* g1 = (const float*)d_in[18];  const float* be1 = (const float*)d_in[19];
    const float* g2 = (const float*)d_in[20];  const float* be2 = (const float*)d_in[21];
    const float* Fq = (const float*)d_in[22];  const float* fbq = (const float*)d_in[23];
    const float* Fk = (const float*)d_in[24];  const float* fbk = (const float*)d_in[25];
    const float* Fv = (const float*)d_in[26];  const float* fbv = (const float*)d_in[27];
    const float* Fout = (const float*)d_in[28]; const float* fbout = (const float*)d_in[29];
    float* out = (float*)d_out;
    float* emb = (float*)d_ws;   // 1048576 floats

    void* kargs[] = {
        (void*)&x, (void*)&mask, (void*)&Wih, (void*)&Whh, (void*)&bih, (void*)&bhh,
        (void*)&Wq, (void*)&bq, (void*)&Wk, (void*)&bk, (void*)&Wv, (void*)&bv,
        (void*)&Wo, (void*)&bo, (void*)&W1, (void*)&b1, (void*)&W2, (void*)&b2,
        (void*)&g1, (void*)&be1, (void*)&g2, (void*)&be2,
        (void*)&Fq, (void*)&fbq, (void*)&Fk, (void*)&fbk, (void*)&Fv, (void*)&fbv,
        (void*)&Fout, (void*)&fbout, (void*)&emb, (void*)&out
    };
    hipLaunchCooperativeKernel((const void*)fused_kernel, dim3(256), dim3(512),
                               kargs, 0, stream);
}

// Round 9
// 229.022 us; speedup vs baseline: 1.4396x; 1.4396x over previous
//
#include <hip/hip_runtime.h>
#include <hip/hip_bf16.h>
#include <math.h>

#define BB 128
#define TT 64
#define DD 64
#define HH 128
#define NHH 4
#define K3H 384        // 3*H

typedef __attribute__((ext_vector_type(8))) short short8_t;   // 8 bf16
typedef __attribute__((ext_vector_type(4))) float float4_t;

#define LOG2E 1.4426950408889634f

__device__ __forceinline__ unsigned short f2bf(float f) {
    unsigned int u = __float_as_uint(f);
    u += 0x7fffu + ((u >> 16) & 1u);      // RNE
    return (unsigned short)(u >> 16);
}

// hardware packed convert: v_cvt_pk_bf16_f32 (RNE, bit-identical to f2bf)
__device__ __forceinline__ unsigned pack_bf2_hw(float lo, float hi) {
    __hip_bfloat162 p = __float22bfloat162_rn(make_float2(lo, hi));
    unsigned u;
    __builtin_memcpy(&u, &p, 4);
    return u;
}

// single-value hw convert: 1 VALU op (vs 4 for software f2bf)
__device__ __forceinline__ unsigned short f2bf_hw(float f) {
    return (unsigned short)(pack_bf2_hw(f, f) & 0xffffu);
}

__device__ __forceinline__ float bf2f(unsigned short s) {
    return __uint_as_float((unsigned)s << 16);
}

// packed-pair fp32 helpers (SLP -> v_pk_fma_f32 / v_pk_add_f32)
__device__ __forceinline__ float2 pk_fma(float2 a, float2 b, float2 c) {
    return make_float2(fmaf(a.x, b.x, c.x), fmaf(a.y, b.y, c.y));
}
__device__ __forceinline__ float2 pk_sub(float2 a, float2 b) {
    return make_float2(a.x - b.x, a.y - b.y);
}

// Shared-reciprocal z/tanh epilogue (verified R4, absmax unchanged).
__device__ __forceinline__ void gru_epilogue(
    const float4_t& ar, const float4_t& az, const float4_t& an, float xv,
    const float wrs[4], const float wzs[4], const float wns[4],
    const float bnis[4], float hprev[4], float hn4[4])
{
    float2 xv2 = make_float2(xv, xv);
#pragma unroll
    for (int pp = 0; pp < 2; ++pp) {
        const int r0 = 2 * pp, r1 = r0 + 1;
        float2 grs = pk_fma(xv2, make_float2(wrs[r0], wrs[r1]),
                            make_float2(ar[r0], ar[r1]));
        float2 gzs = pk_fma(xv2, make_float2(wzs[r0], wzs[r1]),
                            make_float2(az[r0], az[r1]));
        float2 rg = make_float2(
            __builtin_amdgcn_rcpf(1.f + __builtin_amdgcn_exp2f(grs.x)),
            __builtin_amdgcn_rcpf(1.f + __builtin_amdgcn_exp2f(grs.y)));
        float2 gns = pk_fma(rg, make_float2(an[r0], an[r1]),
                            pk_fma(xv2, make_float2(wns[r0], wns[r1]),
                                   make_float2(bnis[r0], bnis[r1])));
        float2 t1 = make_float2(1.f + __builtin_amdgcn_exp2f(gns.x),
                                1.f + __builtin_amdgcn_exp2f(gns.y));
        float2 t2 = make_float2(1.f + __builtin_amdgcn_exp2f(gzs.x),
                                1.f + __builtin_amdgcn_exp2f(gzs.y));
        float2 iD = make_float2(__builtin_amdgcn_rcpf(t1.x * t2.x),
                                __builtin_amdgcn_rcpf(t1.y * t2.y));
        float2 tn = make_float2(fmaf(-2.f, t2.x * iD.x, 1.f),
                                fmaf(-2.f, t2.y * iD.y, 1.f));
        float2 zg = make_float2(t1.x * iD.x, t1.y * iD.y);
        float2 hp = make_float2(hprev[r0], hprev[r1]);
        float2 hn = pk_fma(zg, pk_sub(hp, tn), tn);
        hprev[r0] = hn.x; hprev[r1] = hn.y;
        hn4[r0] = hn.x; hn4[r1] = hn.y;
    }
}

// ---------------- per-feature GRU via bf16 MFMA (R6, frozen, 88us) -------
__global__ __launch_bounds__(512, 1) void gru_mfma_kernel(
    const float* __restrict__ x, const int* __restrict__ mask,
    const float* __restrict__ Wih, const float* __restrict__ Whh,
    const float* __restrict__ bih, const float* __restrict__ bhh,
    float* __restrict__ emb)
{
    const int d  = blockIdx.x;
    const int b0 = blockIdx.y * 32;
    const int tid = threadIdx.x;
    const int w = tid >> 6;           // 0..7 col tile
    const int l = tid & 63;
    const int m = l & 15;
    const int q = l >> 4;

    __shared__ __align__(16) unsigned short hbuf[2][2][16][144]; // [grp][parity]
    __shared__ float xs_t[TT][32];
    __shared__ int tstar_s[32];
    __shared__ char lds_pad_[60 * 1024];
    if (mask[0] == 0x7abcdef) ((volatile char*)lds_pad_)[0] = 1;

    for (int idx = tid; idx < 32 * TT; idx += 512) {
        int t = idx >> 5, row = idx & 31;
        xs_t[t][row] = x[((size_t)(b0 + row) * TT + t) * DD + d];
    }
    if (tid < 32) {
        int b = b0 + tid, len = 0;
        for (int t = 0; t < TT; ++t) len += mask[b * TT + t];
        int ts = len - 1;
        if (ts < 0) ts = 0;
        if (ts > TT - 1) ts = TT - 1;
        tstar_s[tid] = ts;
    }
    for (int idx = tid; idx < 2 * 2 * 16 * 144; idx += 512)
        ((unsigned short*)hbuf)[idx] = 0;

    // Weight fragments: 3 gates x 4 k-chunks, 16 cols per wave (48 VGPRs)
    short8_t Wf[3][4];
#pragma unroll
    for (int g = 0; g < 3; ++g) {
        float sc = (g == 2) ? (2.f * LOG2E) : (-LOG2E);
        int kcol = g * HH + 16 * w + m;
        const float* wrow = Whh + ((size_t)d * K3H + kcol) * HH;
#pragma unroll
        for (int kc = 0; kc < 4; ++kc) {
            int j0 = kc * 32 + q * 8;
            float4 w0 = *(const float4*)(wrow + j0);
            float4 w1 = *(const float4*)(wrow + j0 + 4);
            short8_t f;
            f[0] = (short)f2bf(w0.x * sc); f[1] = (short)f2bf(w0.y * sc);
            f[2] = (short)f2bf(w0.z * sc); f[3] = (short)f2bf(w0.w * sc);
            f[4] = (short)f2bf(w1.x * sc); f[5] = (short)f2bf(w1.y * sc);
            f[6] = (short)f2bf(w1.z * sc); f[7] = (short)f2bf(w1.w * sc);
            Wf[g][kc] = f;
        }
    }

    const int hcol0 = 16 * w + q * 4;
    float4 wr4 = *(const float4*)&Wih[d * K3H + hcol0];
    float4 wz4 = *(const float4*)&Wih[d * K3H + HH + hcol0];
    float4 wn4 = *(const float4*)&Wih[d * K3H + 2 * HH + hcol0];
    float4 br4 = *(const float4*)&bih[d * K3H + hcol0];
    float4 bz4 = *(const float4*)&bih[d * K3H + HH + hcol0];
    float4 bni4 = *(const float4*)&bih[d * K3H + 2 * HH + hcol0];
    float4 bhr4 = *(const float4*)&bhh[d * K3H + hcol0];
    float4 bhz4 = *(const float4*)&bhh[d * K3H + HH + hcol0];
    float4 bnh4 = *(const float4*)&bhh[d * K3H + 2 * HH + hcol0];
    float brs[4], bzs[4], bnis[4], bnhs[4], wrs[4], wzs[4], wns[4];
#pragma unroll
    for (int r = 0; r < 4; ++r) {
        wrs[r] = -LOG2E * ((const float*)&wr4)[r];
        wzs[r] = -LOG2E * ((const float*)&wz4)[r];
        wns[r] = 2.f * LOG2E * ((const float*)&wn4)[r];
        brs[r] = -LOG2E * (((const float*)&br4)[r] + ((const float*)&bhr4)[r]);
        bzs[r] = -LOG2E * (((const float*)&bz4)[r] + ((const float*)&bhz4)[r]);
        bnis[r] = 2.f * LOG2E * ((const float*)&bni4)[r];
        bnhs[r] = 2.f * LOG2E * ((const float*)&bnh4)[r];
    }

    float hprevA[4], hprevB[4];
#pragma unroll
    for (int i = 0; i < 4; ++i) { hprevA[i] = 0.f; hprevB[i] = 0.f; }

    __syncthreads();                       // hbuf zero-init visible
    const int tstarA = tstar_s[m];
    const int tstarB = tstar_s[16 + m];
    float* embpA = emb + (((size_t)(b0 + m)) * DD + d) * HH + hcol0;
    float* embpB = emb + (((size_t)(b0 + 16 + m)) * DD + d) * HH + hcol0;

    short8_t hfA[4];
#pragma unroll
    for (int kc = 0; kc < 4; ++kc)
        hfA[kc] = *(const short8_t*)&hbuf[0][0][m][kc * 32 + q * 8];
    float4_t arA = {brs[0], brs[1], brs[2], brs[3]};
    float4_t azA = {bzs[0], bzs[1], bzs[2], bzs[3]};
    float4_t anA = {bnhs[0], bnhs[1], bnhs[2], bnhs[3]};
#pragma unroll
    for (int kc = 0; kc < 4; ++kc) {
        arA = __builtin_amdgcn_mfma_f32_16x16x32_bf16(Wf[0][kc], hfA[kc], arA, 0, 0, 0);
        azA = __builtin_amdgcn_mfma_f32_16x16x32_bf16(Wf[1][kc], hfA[kc], azA, 0, 0, 0);
        anA = __builtin_amdgcn_mfma_f32_16x16x32_bf16(Wf[2][kc], hfA[kc], anA, 0, 0, 0);
    }

    for (int t = 0; t < TT; ++t) {
        const int par = t & 1;
        float hn4[4];
        uint2 uu;

        short8_t hfB[4];
#pragma unroll
        for (int kc = 0; kc < 4; ++kc)
            hfB[kc] = *(const short8_t*)&hbuf[1][par][m][kc * 32 + q * 8];

        gru_epilogue(arA, azA, anA, xs_t[t][m], wrs, wzs, wns, bnis, hprevA, hn4);
        uu.x = pack_bf2_hw(hn4[0], hn4[1]);
        uu.y = pack_bf2_hw(hn4[2], hn4[3]);
        *(uint2*)&hbuf[0][par ^ 1][m][hcol0] = uu;
        if (t == tstarA) {
            float4 hv; hv.x = hn4[0]; hv.y = hn4[1]; hv.z = hn4[2]; hv.w = hn4[3];
            *(float4*)embpA = hv;
        }

        float4_t arB = {brs[0], brs[1], brs[2], brs[3]};
        float4_t azB = {bzs[0], bzs[1], bzs[2], bzs[3]};
        float4_t anB = {bnhs[0], bnhs[1], bnhs[2], bnhs[3]};
#pragma unroll
        for (int kc = 0; kc < 4; ++kc) {
            arB = __builtin_amdgcn_mfma_f32_16x16x32_bf16(Wf[0][kc], hfB[kc], arB, 0, 0, 0);
            azB = __builtin_amdgcn_mfma_f32_16x16x32_bf16(Wf[1][kc], hfB[kc], azB, 0, 0, 0);
            anB = __builtin_amdgcn_mfma_f32_16x16x32_bf16(Wf[2][kc], hfB[kc], anB, 0, 0, 0);
        }

        gru_epilogue(arB, azB, anB, xs_t[t][16 + m], wrs, wzs, wns, bnis, hprevB, hn4);
        uu.x = pack_bf2_hw(hn4[0], hn4[1]);
        uu.y = pack_bf2_hw(hn4[2], hn4[3]);
        *(uint2*)&hbuf[1][par ^ 1][m][hcol0] = uu;
        if (t == tstarB) {
            float4 hv; hv.x = hn4[0]; hv.y = hn4[1]; hv.z = hn4[2]; hv.w = hn4[3];
            *(float4*)embpB = hv;
        }

        __syncthreads();

        if (t < TT - 1) {
#pragma unroll
            for (int kc = 0; kc < 4; ++kc)
                hfA[kc] = *(const short8_t*)&hbuf[0][par ^ 1][m][kc * 32 + q * 8];
            arA = (float4_t){brs[0], brs[1], brs[2], brs[3]};
            azA = (float4_t){bzs[0], bzs[1], bzs[2], bzs[3]};
            anA = (float4_t){bnhs[0], bnhs[1], bnhs[2], bnhs[3]};
#pragma unroll
            for (int kc = 0; kc < 4; ++kc) {
                arA = __builtin_amdgcn_mfma_f32_16x16x32_bf16(Wf[0][kc], hfA[kc], arA, 0, 0, 0);
                azA = __builtin_amdgcn_mfma_f32_16x16x32_bf16(Wf[1][kc], hfA[kc], azA, 0, 0, 0);
                anA = __builtin_amdgcn_mfma_f32_16x16x32_bf16(Wf[2][kc], hfA[kc], anA, 0, 0, 0);
            }
        }
    }
}

// ============ weight pre-conversion: fragment-ordered bf16 ================
// 10 virtual matrices, each 128 rows x 128 cols.  Output layout per matrix:
// elem index = col*128 + kc*32 + q*8 + j  (matches MFMA fragment read:
// one short8 = 16B contiguous per (col,kc,q)).  Same RNE convert as R7 ->
// bit-identical tail numerics.
__global__ __launch_bounds__(512) void preconv_kernel(
    const float* __restrict__ Wq, const float* __restrict__ Wk,
    const float* __restrict__ Wv, const float* __restrict__ Wo,
    const float* __restrict__ W1, const float* __restrict__ W2,
    const float* __restrict__ Fk, const float* __restrict__ Fv,
    unsigned short* __restrict__ wpre)
{
    const int m = blockIdx.x;
    const float SS = 0.17677669529663687f;
    const float* base; int stride, colofs; float scale = 1.f;
    switch (m) {
        case 0: base = Wq; stride = 128; colofs = 0;   scale = SS; break;
        case 1: base = Wk; stride = 128; colofs = 0;   break;
        case 2: base = Wv; stride = 128; colofs = 0;   break;
        case 3: base = Wo; stride = 128; colofs = 0;   break;
        case 4: base = W1; stride = 256; colofs = 0;   break;
        case 5: base = W1; stride = 256; colofs = 128; break;
        case 6: base = W2;                stride = 128; colofs = 0; break;
        case 7: base = W2 + 128 * 128;    stride = 128; colofs = 0; break;
        case 8: base = Fk; stride = 128; colofs = 0;   break;
        default: base = Fv; stride = 128; colofs = 0;  break;
    }
    unsigned short* out = wpre + (size_t)m * 16384;
    for (int e = threadIdx.x; e < 16384; e += 512) {
        int col = e >> 7, r = e & 127;       // r = kc*32 + q*8 + j
        float v = base[(size_t)r * stride + colofs + col] * scale;
        out[e] = f2bf_hw(v);
    }
}

// ============ fused tail v4: prepacked weights ============================
__device__ __forceinline__ void load_wfrag_pre(const unsigned short* __restrict__ Wp,
                                               int col, int q, short8_t fr[4])
{
    const unsigned short* p = Wp + ((size_t)col << 7) + q * 8;
#pragma unroll
    for (int kc = 0; kc < 4; ++kc)
        fr[kc] = *(const short8_t*)(p + kc * 32);
}

__device__ __forceinline__ void load_afrag(const unsigned short (*S)[136],
                                           short8_t Af[4][4], int m16, int q)
{
#pragma unroll
    for (int mt = 0; mt < 4; ++mt)
#pragma unroll
        for (int kc = 0; kc < 4; ++kc)
            Af[mt][kc] = *(const short8_t*)&S[mt * 16 + m16][kc * 32 + q * 8];
}

__device__ __forceinline__ void mm_regw(short8_t Af[4][4], short8_t Bf[4],
                                        float4_t acc[4])
{
#pragma unroll
    for (int mt = 0; mt < 4; ++mt) {
        float4_t a = acc[mt];
#pragma unroll
        for (int kc = 0; kc < 4; ++kc)
            a = __builtin_amdgcn_mfma_f32_16x16x32_bf16(Af[mt][kc], Bf[kc], a, 0, 0, 0);
        acc[mt] = a;
    }
}

__device__ __forceinline__ void zero4(float4_t acc[4]) {
#pragma unroll
    for (int mt = 0; mt < 4; ++mt) acc[mt] = (float4_t){0.f, 0.f, 0.f, 0.f};
}

__device__ __forceinline__ void store_rows(unsigned short (*Dst)[136], float4_t acc[4],
                                           float bv, int relu, int col, int q)
{
#pragma unroll
    for (int mt = 0; mt < 4; ++mt)
#pragma unroll
        for (int reg = 0; reg < 4; ++reg) {
            float v = acc[mt][reg] + bv;
            if (relu) v = fmaxf(v, 0.f);
            Dst[mt * 16 + q * 4 + reg][col] = f2bf_hw(v);
        }
}

__global__ __launch_bounds__(512) void tail_kernel(
    const float* __restrict__ emb, const unsigned short* __restrict__ wpre,
    const float* __restrict__ bq, const float* __restrict__ bk,
    const float* __restrict__ bv, const float* __restrict__ bo,
    const float* __restrict__ b1, const float* __restrict__ b2,
    const float* __restrict__ g1, const float* __restrict__ be1,
    const float* __restrict__ g2, const float* __restrict__ be2,
    const float* __restrict__ Fq, const float* __restrict__ fbq,
    const float* __restrict__ fbk, const float* __restrict__ fbv,
    const float* __restrict__ Fout, const float* __restrict__ fbout,
    float* __restrict__ out)
{
    const int b = blockIdx.x;
    const int tid = threadIdx.x;
    const int w = tid >> 6, l = tid & 63, m16 = l & 15, q = l >> 4;
    const int col = w * 16 + m16;

    __shared__ __align__(16) unsigned short E[64][136];   // emb->o->h1->h2
    __shared__ __align__(16) unsigned short Qs[64][136];  // q->P01->a1lo->fk
    __shared__ __align__(16) unsigned short Ks[64][136];  // k->P23->a1hi->fv
    __shared__ __align__(16) unsigned short Vt[128][72];  // V transposed
    __shared__ float sc4[4][64][66];                      // scores, 4 heads
    __shared__ float lnp[64][8], lnp2[64][8];
    __shared__ float mean_s[64], rs_s[64];
    __shared__ float fq_s[128], fo_s[128], e_s[64], red_s[256];

    const float* embB = emb + (size_t)b * 64 * 128;
    const float SS = 0.17677669529663687f;   // 1/sqrt(32)

    const unsigned short* WQp = wpre;
    const unsigned short* WKp = wpre + 16384;
    const unsigned short* WVp = wpre + 2 * 16384;
    const unsigned short* WOp = wpre + 3 * 16384;
    const unsigned short* W1a = wpre + 4 * 16384;
    const unsigned short* W1b = wpre + 5 * 16384;
    const unsigned short* W2a = wpre + 6 * 16384;
    const unsigned short* W2b = wpre + 7 * 16384;
    const unsigned short* FKp = wpre + 8 * 16384;
    const unsigned short* FVp = wpre + 9 * 16384;

    short8_t WqF[4], WkF[4], WvF[4];
    load_wfrag_pre(WQp, col, q, WqF);
    load_wfrag_pre(WKp, col, q, WkF);
    load_wfrag_pre(WVp, col, q, WvF);
    float bqv = bq[col] * SS, bkv = bk[col], bvv = bv[col];

    for (int it = tid; it < 2048; it += 512) {
        int r = it >> 5, c4 = (it & 31) << 2;
        float4 a = *(const float4*)&embB[r * 128 + c4];
        uint2 p; p.x = pack_bf2_hw(a.x, a.y); p.y = pack_bf2_hw(a.z, a.w);
        *(uint2*)&E[r][c4] = p;
    }
    __syncthreads();                                   // B0

    short8_t Af[4][4];
    float4_t acc[4];
    load_afrag(E, Af, m16, q);

    zero4(acc); mm_regw(Af, WqF, acc); store_rows(Qs, acc, bqv, 0, col, q);
    zero4(acc); mm_regw(Af, WkF, acc); store_rows(Ks, acc, bkv, 0, col, q);
    zero4(acc); mm_regw(Af, WvF, acc);
#pragma unroll
    for (int mt = 0; mt < 4; ++mt) {
        uint2 pk;
        pk.x = pack_bf2_hw(acc[mt][0] + bvv, acc[mt][1] + bvv);
        pk.y = pack_bf2_hw(acc[mt][2] + bvv, acc[mt][3] + bvv);
        *(uint2*)&Vt[col][mt * 16 + q * 4] = pk;
    }
    __syncthreads();                                   // B1

    short8_t WoF[4], W1aF[4], W1bF[4];
    load_wfrag_pre(WOp, col, q, WoF);
    load_wfrag_pre(W1a, col, q, W1aF);
    load_wfrag_pre(W1b, col, q, W1bF);
    float bov = bo[col], b1a = b1[col], b1b = b1[128 + col];
    float g1v = g1[col], be1v = be1[col];

    {
        int hd = w >> 1, ntb = (w & 1) * 2;
#pragma unroll
        for (int mt = 0; mt < 4; ++mt) {
            short8_t Aq = *(const short8_t*)&Qs[mt * 16 + m16][hd * 32 + q * 8];
#pragma unroll
            for (int nn = 0; nn < 2; ++nn) {
                int nt = ntb + nn;
                short8_t Bk = *(const short8_t*)&Ks[nt * 16 + m16][hd * 32 + q * 8];
                float4_t a = {0.f, 0.f, 0.f, 0.f};
                a = __builtin_amdgcn_mfma_f32_16x16x32_bf16(Aq, Bk, a, 0, 0, 0);
#pragma unroll
                for (int reg = 0; reg < 4; ++reg)
                    sc4[hd][mt * 16 + q * 4 + reg][nt * 16 + m16] = a[reg];
            }
        }
    }
    __syncthreads();                                   // B2

    {
        int pr = tid >> 1, hd2 = pr >> 6, row = pr & 63, half = (tid & 1) * 32;
        float v[32]; float mx = -1e30f;
#pragma unroll
        for (int c = 0; c < 32; ++c) { v[c] = sc4[hd2][row][half + c]; mx = fmaxf(mx, v[c]); }
        mx = fmaxf(mx, __shfl_xor(mx, 1));
        float sum = 0.f;
#pragma unroll
        for (int c = 0; c < 32; ++c) { v[c] = __expf(v[c] - mx); sum += v[c]; }
        sum += __shfl_xor(sum, 1);
        float inv = __builtin_amdgcn_rcpf(sum);
        unsigned short (*Pd)[136] = (hd2 < 2) ? Qs : Ks;
        int cb = (hd2 & 1) * 64 + half;
#pragma unroll
        for (int c = 0; c < 16; ++c)
            *(unsigned*)&Pd[row][cb + 2 * c] = pack_bf2_hw(v[2 * c] * inv, v[2 * c + 1] * inv);
    }
    __syncthreads();                                   // B3

    {
        int hd = w >> 1, nt = w & 1;
        const unsigned short (*P)[136] = (hd < 2) ? (const unsigned short (*)[136])Qs
                                                  : (const unsigned short (*)[136])Ks;
        int pb = (hd & 1) * 64;
        int vrow = hd * 32 + nt * 16 + m16;
        short8_t B0f = *(const short8_t*)&Vt[vrow][q * 8];
        short8_t B1f = *(const short8_t*)&Vt[vrow][32 + q * 8];
#pragma unroll
        for (int mt = 0; mt < 4; ++mt) {
            short8_t A0 = *(const short8_t*)&P[mt * 16 + m16][pb + q * 8];
            short8_t A1 = *(const short8_t*)&P[mt * 16 + m16][pb + 32 + q * 8];
            float4_t a = {0.f, 0.f, 0.f, 0.f};
            a = __builtin_amdgcn_mfma_f32_16x16x32_bf16(A0, B0f, a, 0, 0, 0);
            a = __builtin_amdgcn_mfma_f32_16x16x32_bf16(A1, B1f, a, 0, 0, 0);
#pragma unroll
            for (int reg = 0; reg < 4; ++reg)
                E[mt * 16 + q * 4 + reg][vrow] = f2bf_hw(a[reg]);
        }
    }
    __syncthreads();                                   // B4

    short8_t W2aF[4], W2bF[4], FkF[4], FvF[4];
    load_wfrag_pre(W2a, col, q, W2aF);
    load_wfrag_pre(W2b, col, q, W2bF);
    load_wfrag_pre(FKp, col, q, FkF);
    load_wfrag_pre(FVp, col, q, FvF);
    float b2v = b2[col], fbkv = fbk[col], fbvv = fbv[col];
    float g2v = g2[col], be2v = be2[col];

    load_afrag(E, Af, m16, q);
    zero4(acc); mm_regw(Af, WoF, acc);
    float h1v[4][4];
#pragma unroll
    for (int mt = 0; mt < 4; ++mt)
#pragma unroll
        for (int reg = 0; reg < 4; ++reg) {
            int row = mt * 16 + q * 4 + reg;
            h1v[mt][reg] = acc[mt][reg] + bov + embB[(size_t)row * 128 + col];
        }
#pragma unroll
    for (int mt = 0; mt < 4; ++mt)
#pragma unroll
        for (int reg = 0; reg < 4; ++reg) {
            float s = h1v[mt][reg], s2 = s * s;
            s += __shfl_xor(s, 1); s += __shfl_xor(s, 2); s += __shfl_xor(s, 4); s += __shfl_xor(s, 8);
            s2 += __shfl_xor(s2, 1); s2 += __shfl_xor(s2, 2); s2 += __shfl_xor(s2, 4); s2 += __shfl_xor(s2, 8);
            if (m16 == 0) { int row = mt * 16 + q * 4 + reg; lnp[row][w] = s; lnp2[row][w] = s2; }
        }
    __syncthreads();                                   // B5
    if (tid < 64) {
        float s = 0.f, s2 = 0.f;
#pragma unroll
        for (int k = 0; k < 8; ++k) { s += lnp[tid][k]; s2 += lnp2[tid][k]; }
        float mn = s * (1.f / 128.f);
        mean_s[tid] = mn;
        rs_s[tid] = rsqrtf(s2 * (1.f / 128.f) - mn * mn + 1e-5f);
    }
    __syncthreads();                                   // B6
#pragma unroll
    for (int mt = 0; mt < 4; ++mt)
#pragma unroll
        for (int reg = 0; reg < 4; ++reg) {
            int row = mt * 16 + q * 4 + reg;
            float hv = (h1v[mt][reg] - mean_s[row]) * rs_s[row] * g1v + be1v;
            h1v[mt][reg] = hv;
            E[row][col] = f2bf_hw(hv);
        }
    __syncthreads();                                   // B7

    load_afrag(E, Af, m16, q);
    zero4(acc); mm_regw(Af, W1aF, acc); store_rows(Qs, acc, b1a, 1, col, q);
    zero4(acc); mm_regw(Af, W1bF, acc); store_rows(Ks, acc, b1b, 1, col, q);
    __syncthreads();                                   // B8

    {
        short8_t AfQ[4][4], AfK[4][4];
        load_afrag(Qs, AfQ, m16, q);
        load_afrag(Ks, AfK, m16, q);
        zero4(acc); mm_regw(AfQ, W2aF, acc); mm_regw(AfK, W2bF, acc);
    }
#pragma unroll
    for (int mt = 0; mt < 4; ++mt)
#pragma unroll
        for (int reg = 0; reg < 4; ++reg)
            h1v[mt][reg] = acc[mt][reg] + b2v + h1v[mt][reg];
#pragma unroll
    for (int mt = 0; mt < 4; ++mt)
#pragma unroll
        for (int reg = 0; reg < 4; ++reg) {
            float s = h1v[mt][reg], s2 = s * s;
            s += __shfl_xor(s, 1); s += __shfl_xor(s, 2); s += __shfl_xor(s, 4); s += __shfl_xor(s, 8);
            s2 += __shfl_xor(s2, 1); s2 += __shfl_xor(s2, 2); s2 += __shfl_xor(s2, 4); s2 += __shfl_xor(s2, 8);
            if (m16 == 0) { int row = mt * 16 + q * 4 + reg; lnp[row][w] = s; lnp2[row][w] = s2; }
        }
    __syncthreads();                                   // B9
    if (tid < 64) {
        float s = 0.f, s2 = 0.f;
#pragma unroll
        for (int k = 0; k < 8; ++k) { s += lnp[tid][k]; s2 += lnp2[tid][k]; }
        float mn = s * (1.f / 128.f);
        mean_s[tid] = mn;
        rs_s[tid] = rsqrtf(s2 * (1.f / 128.f) - mn * mn + 1e-5f);
    }
    __syncthreads();                                   // B10
#pragma unroll
    for (int mt = 0; mt < 4; ++mt)
#pragma unroll
        for (int reg = 0; reg < 4; ++reg) {
            int row = mt * 16 + q * 4 + reg;
            float hv = (h1v[mt][reg] - mean_s[row]) * rs_s[row] * g2v + be2v;
            E[row][col] = f2bf_hw(hv);   // h2
        }
    __syncthreads();                                   // B11

    load_afrag(E, Af, m16, q);
    zero4(acc); mm_regw(Af, FkF, acc); store_rows(Qs, acc, fbkv, 0, col, q);
    zero4(acc); mm_regw(Af, FvF, acc); store_rows(Ks, acc, fbvv, 0, col, q);
    {
        int co = tid >> 2, sub = tid & 3;
        float a2 = 0.f;
#pragma unroll 8
        for (int mm2 = sub * 32; mm2 < sub * 32 + 32; ++mm2)
            a2 = fmaf(bf2f(E[63][mm2]), Fq[(size_t)mm2 * 128 + co], a2);
        a2 += __shfl_xor(a2, 1);
        a2 += __shfl_xor(a2, 2);
        if (sub == 0) fq_s[co] = a2 + fbq[co];
    }
    if (tid < 128) fo_s[tid] = Fout[tid];
    __syncthreads();                                   // B12

    {
        int dd = tid >> 3, c8 = tid & 7;
        float p = 0.f;
#pragma unroll
        for (int c = 0; c < 16; ++c) {
            int cc = c8 * 16 + c;
            float t = fq_s[cc] + bf2f(Qs[dd][cc]);
            float tn = 1.f - 2.f * __builtin_amdgcn_rcpf(
                __builtin_amdgcn_exp2f(2.f * LOG2E * t) + 1.f);
            p = fmaf(tn, fo_s[cc], p);
        }
        p += __shfl_xor(p, 1); p += __shfl_xor(p, 2); p += __shfl_xor(p, 4);
        if (c8 == 0) e_s[dd] = p + fbout[0];
    }
    __syncthreads();                                   // B13
    if (tid < 64) {
        float e = e_s[tid], mx = e;
        for (int o = 32; o; o >>= 1) mx = fmaxf(mx, __shfl_xor(mx, o));
        float pe = __expf(e - mx);
        float s = pe;
        for (int o = 32; o; o >>= 1) s += __shfl_xor(s, o);
        e_s[tid] = pe / s;
    }
    __syncthreads();                                   // B14
    if (tid < 256) {
        int c2 = tid & 127, rg2 = tid >> 7;
        float a = 0.f;
        for (int d2 = rg2 * 32; d2 < rg2 * 32 + 32; ++d2)
            a = fmaf(e_s[d2], bf2f(Ks[d2][c2]), a);
        red_s[tid] = a;
    }
    __syncthreads();                                   // B15
    if (tid < 128)
        out[(size_t)b * 128 + tid] = red_s[tid] + red_s[tid + 128];
}

// ---------------- launch ---------------------------------------------------
extern "C" void kernel_launch(void* const* d_in, const int* in_sizes, int n_in,
                              void* d_out, int out_size, void* d_ws, size_t ws_size,
                              hipStream_t stream)
{
    const float* x    = (const float*)d_in[0];
    const int*   mask = (const int*)d_in[1];
    const float* Wih  = (const float*)d_in[2];
    const float* Whh  = (const float*)d_in[3];
    const float* bih  = (const float*)d_in[4];
    const float* bhh  = (const float*)d_in[5];
    const float* Wq = (const float*)d_in[6];   const float* bq = (const float*)d_in[7];
    const float* Wk = (const float*)d_in[8];   const float* bk = (const float*)d_in[9];
    const float* Wv = (const float*)d_in[10];  const float* bv = (const float*)d_in[11];
    const float* Wo = (const float*)d_in[12];  const float* bo = (const float*)d_in[13];
    const float* W1 = (const float*)d_in[14];  const float* b1 = (const float*)d_in[15];
    const float* W2 = (const float*)d_in[16];  const float* b2 = (const float*)d_in[17];
    const float* g1 = (const float*)d_in[18];  const float* be1 = (const float*)d_in[19];
    const float* g2 = (const float*)d_in[20];  const float* be2 = (const float*)d_in[21];
    const float* Fq = (const float*)d_in[22];  const float* fbq = (const float*)d_in[23];
    const float* Fk = (const float*)d_in[24];  const float* fbk = (const float*)d_in[25];
    const float* Fv = (const float*)d_in[26];  const float* fbv = (const float*)d_in[27];
    const float* Fout = (const float*)d_in[28]; const float* fbout = (const float*)d_in[29];
    float* out = (float*)d_out;
    float* ws  = (float*)d_ws;

    float* emb = ws;                                        // 1048576 floats (4 MB)
    unsigned short* wpre = (unsigned short*)(ws + 1048576); // 10*16384 bf16 (320 KB)

    preconv_kernel<<<dim3(10), 512, 0, stream>>>(Wq, Wk, Wv, Wo, W1, W2, Fk, Fv, wpre);
    gru_mfma_kernel<<<dim3(DD, BB / 32), 512, 0, stream>>>(x, mask, Wih, Whh, bih, bhh, emb);
    tail_kernel<<<BB, 512, 0, stream>>>(
        emb, wpre, bq, bk, bv, bo, b1, b2,
        g1, be1, g2, be2, Fq, fbq, fbk, fbv, Fout, fbout, out);
}